// Round 4
// baseline (461.595 us; speedup 1.0000x reference)
//
#include <hip/hip_runtime.h>
#include <math.h>

#define CIN    64
#define OUTC   64
#define BOT    16
#define KK     9
#define HH     48
#define WW     48
#define LPIX   (HH*WW)      // 2304
#define WSZ    9216
#define PSZ    1024
#define PREDCH 10304
#define GRPSZ  2576
#define BATCH  2
#define CPAD   68           // patch/part row stride (floats)
#define PLD    620          // Pl per-d stride in ushorts (9*68 + 8): conflict-free phase-3
#define QST    68           // Qm per-j stride in ushorts

__device__ inline float bf2f(unsigned short u) {
    return __uint_as_float(((unsigned int)u) << 16);
}
__device__ inline unsigned short f2bf(float f) {
    unsigned int u = __float_as_uint(f);
    return (unsigned short)((u + 0x7FFFu + ((u >> 16) & 1u)) >> 16);   // RNE
}
__device__ inline float bfl(unsigned int u) { return __uint_as_float(u << 16); }
__device__ inline float bfh(unsigned int u) { return __uint_as_float(u & 0xFFFF0000u); }

// Pre-kernel: Wp fp32 -> bf16 (halves phase-2 L2 traffic).
__global__ __launch_bounds__(256) void cvt_wp(const float* __restrict__ Wp,
                                              unsigned short* __restrict__ Wb) {
    const int n = PREDCH * 16;
    for (int i = blockIdx.x * 256 + threadIdx.x; i < n; i += gridDim.x * 256)
        Wb[i] = f2bf(Wp[i]);
}

// 2 adjacent pixels / block, 576 threads. LDS ~59 KB.
// P2: fixed-g threads, center x in REGISTERS (no LDS reads).
// P3: Gram packed-tri + s_t, conflict-free b64 reads of bf16 P.
// P4: 288 threads, 4 outputs each; G streamed once per 4 o's; partials -> reduce.
__global__ __launch_bounds__(576, 5) void dppc4(
    const float* __restrict__ x,
    const unsigned short* __restrict__ Wb,
    const float* __restrict__ bp,
    float* __restrict__ out)
{
    __shared__ float          patchpart[2 * KK * CPAD];     // 4896 B: patch, then part
    __shared__ unsigned short Pl[2 * BOT * PLD];            // 39680 B (bf16)
    __shared__ float          Gp[2 * KK * 136];             // 9792 B packed upper-tri
    __shared__ float          Sv[2 * KK * 16];              // 1152 B
    __shared__ unsigned short Qm[2 * BOT * QST];            // 4352 B (bf16, [px][j][o])
    __shared__ float          dynb[2 * OUTC];               // 512 B

    float* patch = patchpart;        // valid phases 1-3
    float* part  = patchpart;        // valid phase 4 (patch dead)

    const int tid = threadIdx.x;
    const int pix0 = blockIdx.x * 2;
    const int b  = pix0 / LPIX;
    const int l0 = pix0 - b * LPIX;
    const int h  = l0 / WW;
    const int w0 = l0 - h * WW;

    // ---- Phase 1: 3x3 patches -> LDS [px][t][c] ----
    const float* xb = x + (size_t)b * CIN * LPIX;
    for (int m = tid; m < 2 * CIN * KK; m += 576) {
        const int px = m / (CIN * KK);
        const int r  = m - px * (CIN * KK);
        const int c  = r / KK;
        const int t  = r - c * KK;
        const int hi = h + t / 3 - 1;
        const int wi = w0 + px + (t % 3) - 1;
        float v = 0.0f;
        if (hi >= 0 && hi < HH && wi >= 0 && wi < WW)
            v = xb[c * LPIX + hi * WW + wi];
        patch[(px * KK + t) * CPAD + c] = v;
    }
    __syncthreads();

    // ---- Phase 2: grouped 1x1 conv; center-x preloaded to registers ----
    {
        const int g    = tid / 144;          // fixed channel-group per thread
        const int lane = tid - g * 144;
        const float* xc0 = &patch[(0 * KK + 4) * CPAD + g * 16];
        const float* xc1 = &patch[(1 * KK + 4) * CPAD + g * 16];
        float a[16], c2[16];
        #pragma unroll
        for (int k = 0; k < 4; ++k) {
            const float4 u = *(const float4*)(xc0 + 4 * k);
            a[4*k] = u.x; a[4*k+1] = u.y; a[4*k+2] = u.z; a[4*k+3] = u.w;
            const float4 v = *(const float4*)(xc1 + 4 * k);
            c2[4*k] = v.x; c2[4*k+1] = v.y; c2[4*k+2] = v.z; c2[4*k+3] = v.w;
        }
        #pragma unroll 1
        for (int it = 0; it < 18; ++it) {
            if (it == 17 && lane >= 128) break;   // 2576 = 17*144 + 128
            const int ch = g * GRPSZ + it * 144 + lane;
            const uint4* wr = (const uint4*)(Wb + (size_t)ch * 16);
            const uint4 ua = wr[0], ub = wr[1];
            float wv[16];
            wv[0]=bfl(ua.x);  wv[1]=bfh(ua.x);  wv[2]=bfl(ua.y);  wv[3]=bfh(ua.y);
            wv[4]=bfl(ua.z);  wv[5]=bfh(ua.z);  wv[6]=bfl(ua.w);  wv[7]=bfh(ua.w);
            wv[8]=bfl(ub.x);  wv[9]=bfh(ub.x);  wv[10]=bfl(ub.y); wv[11]=bfh(ub.y);
            wv[12]=bfl(ub.z); wv[13]=bfh(ub.z); wv[14]=bfl(ub.w); wv[15]=bfh(ub.w);
            const float bias = bp[ch];
            float s0 = bias, s1 = bias;
            #pragma unroll
            for (int k = 0; k < 16; ++k) { s0 += wv[k] * a[k]; s1 += wv[k] * c2[k]; }

            if (ch < WSZ) {
                const int d  = ch / 576;
                const int r2 = ch - d * 576;
                const int c  = r2 / 9;
                const int t  = r2 - c * 9;
                Pl[(0 * BOT + d) * PLD + t * CPAD + c] = f2bf(s0);
                Pl[(1 * BOT + d) * PLD + t * CPAD + c] = f2bf(s1);
            } else if (ch < WSZ + PSZ) {
                const int i = ch - WSZ;
                const int o = i >> 4;
                const int j = i & 15;
                Qm[(0 * BOT + j) * QST + o] = f2bf(s0);
                Qm[(1 * BOT + j) * QST + o] = f2bf(s1);
            } else {
                const int o = ch - WSZ - PSZ;
                dynb[0 * OUTC + o] = s0;
                dynb[1 * OUTC + o] = s1;
            }
        }
    }
    __syncthreads();

    // ---- Phase 3: Gram (packed tri) + s_t; 288 threads, 4x4 reg tiles ----
    if (tid < 288) {
        const int px = tid / 144;
        const int r  = tid - px * 144;
        const int t  = r >> 4;          // 0..8
        const int q4 = r & 15;
        const int ib = q4 >> 2;
        const int jb = q4 & 3;

        const ushort4* Ar[4];
        const ushort4* Br[4];
        #pragma unroll
        for (int a = 0; a < 4; ++a) {
            Ar[a] = (const ushort4*)&Pl[(px * BOT + 4 * ib + a) * PLD + t * CPAD];
            Br[a] = (const ushort4*)&Pl[(px * BOT + 4 * jb + a) * PLD + t * CPAD];
        }
        const float4* prow = (const float4*)&patch[(px * KK + t) * CPAD];

        float acc[4][4] = {};
        float sacc[4]   = {0.f, 0.f, 0.f, 0.f};
        for (int cc = 0; cc < 16; ++cc) {
            float A[4][4], B[4][4];
            #pragma unroll
            for (int a = 0; a < 4; ++a) {
                const ushort4 u = Ar[a][cc];
                A[a][0] = bf2f(u.x); A[a][1] = bf2f(u.y);
                A[a][2] = bf2f(u.z); A[a][3] = bf2f(u.w);
            }
            #pragma unroll
            for (int a = 0; a < 4; ++a) {
                const ushort4 u = Br[a][cc];
                B[a][0] = bf2f(u.x); B[a][1] = bf2f(u.y);
                B[a][2] = bf2f(u.z); B[a][3] = bf2f(u.w);
            }
            #pragma unroll
            for (int a = 0; a < 4; ++a)
                #pragma unroll
                for (int bb = 0; bb < 4; ++bb)
                    #pragma unroll
                    for (int k = 0; k < 4; ++k)
                        acc[a][bb] += A[a][k] * B[bb][k];
            if (jb == 0) {
                const float4 p = prow[cc];
                #pragma unroll
                for (int a = 0; a < 4; ++a)
                    sacc[a] += A[a][0]*p.x + A[a][1]*p.y + A[a][2]*p.z + A[a][3]*p.w;
            }
        }
        if (ib <= jb) {
            float* g = &Gp[(px * KK + t) * 136];
            #pragma unroll
            for (int a = 0; a < 4; ++a) {
                const int i = 4 * ib + a;
                const int base = 15 * i - (i * (i - 1)) / 2;
                #pragma unroll
                for (int bb = 0; bb < 4; ++bb) {
                    const int j = 4 * jb + bb;
                    if (j >= i) g[base + j] = acc[a][bb];
                }
            }
        }
        if (jb == 0) {
            #pragma unroll
            for (int a = 0; a < 4; ++a) Sv[(px * KK + t) * 16 + 4 * ib + a] = sacc[a];
        }
    }
    __syncthreads();

    // ---- Phase 4: 288 threads = (px, t, otile); 4 outputs each ----
    if (tid < 288) {
        const int px = tid / 144;
        const int r  = tid - px * 144;
        const int t  = r >> 4;          // 0..8
        const int ot = r & 15;
        const int o0 = ot * 4;

        float4 q4[16];
        #pragma unroll
        for (int j = 0; j < 16; ++j) {
            const ushort4 u = *(const ushort4*)&Qm[(px * BOT + j) * QST + o0];
            q4[j] = make_float4(bf2f(u.x), bf2f(u.y), bf2f(u.z), bf2f(u.w));
        }
        const float* g = &Gp[(px * KK + t) * 136];
        float4 nrm2 = make_float4(0.f, 0.f, 0.f, 0.f);
        int off = 0;
        #pragma unroll
        for (int i = 0; i < 16; ++i) {
            float gd = g[off];
            float4 ui = make_float4(gd*q4[i].x, gd*q4[i].y, gd*q4[i].z, gd*q4[i].w);
            #pragma unroll
            for (int j = i + 1; j < 16; ++j) {
                const float gv = g[off + (j - i)];
                const float g2 = gv + gv;
                ui.x += g2 * q4[j].x; ui.y += g2 * q4[j].y;
                ui.z += g2 * q4[j].z; ui.w += g2 * q4[j].w;
            }
            nrm2.x += ui.x * q4[i].x; nrm2.y += ui.y * q4[i].y;
            nrm2.z += ui.z * q4[i].z; nrm2.w += ui.w * q4[i].w;
            off += 16 - i;
        }
        const float* s = &Sv[(px * KK + t) * 16];
        float4 dp = make_float4(0.f, 0.f, 0.f, 0.f);
        #pragma unroll
        for (int j = 0; j < 16; ++j) {
            const float sj = s[j];
            dp.x += sj * q4[j].x; dp.y += sj * q4[j].y;
            dp.z += sj * q4[j].z; dp.w += sj * q4[j].w;
        }
        float4 res;
        res.x = dp.x / fmaxf(sqrtf(fmaxf(nrm2.x, 0.f)), 1e-12f);
        res.y = dp.y / fmaxf(sqrtf(fmaxf(nrm2.y, 0.f)), 1e-12f);
        res.z = dp.z / fmaxf(sqrtf(fmaxf(nrm2.z, 0.f)), 1e-12f);
        res.w = dp.w / fmaxf(sqrtf(fmaxf(nrm2.w, 0.f)), 1e-12f);
        *(float4*)&part[(px * KK + t) * CPAD + o0] = res;
    }
    __syncthreads();

    // ---- Phase 5: reduce over t, add dyn_b, write out ----
    if (tid < 128) {
        const int px = tid >> 6;
        const int o  = tid & 63;
        float acc = dynb[px * OUTC + o];
        #pragma unroll
        for (int t = 0; t < KK; ++t) acc += part[(px * KK + t) * CPAD + o];
        out[((size_t)b * OUTC + o) * LPIX + l0 + px] = acc;
    }
}

extern "C" void kernel_launch(void* const* d_in, const int* in_sizes, int n_in,
                              void* d_out, int out_size, void* d_ws, size_t ws_size,
                              hipStream_t stream) {
    const float* x  = (const float*)d_in[0];
    const float* Wp = (const float*)d_in[1];
    const float* bp = (const float*)d_in[2];
    float* out = (float*)d_out;
    unsigned short* Wb = (unsigned short*)d_ws;   // PREDCH*16 bf16 = 330 KB
    (void)in_sizes; (void)n_in; (void)out_size; (void)ws_size;

    hipLaunchKernelGGL(cvt_wp, dim3((PREDCH * 16 + 255) / 256), dim3(256), 0, stream, Wp, Wb);
    hipLaunchKernelGGL(dppc4, dim3(BATCH * LPIX / 2), dim3(576), 0, stream, x, Wb, bp, out);
}

// Round 5
// 155.032 us; speedup vs baseline: 2.9774x; 2.9774x over previous
//
#include <hip/hip_runtime.h>
#include <math.h>

#define CIN    64
#define OUTC   64
#define BOT    16
#define KK     9
#define HH     48
#define WW     48
#define LPIX   (HH*WW)
#define WSZ    9216
#define PSZ    1024
#define PREDCH 10304
#define GRPSZ  2576
#define BATCH  2
#define NPX    18          // 3 rows x 6 cols of pixels per block
#define PXS    1160        // Pt px-stride (ushorts): 16*72 + 8
#define QBS    1028        // Qb px-stride (ushorts): 64*16 + 4
#define GS     273         // G px-stride (floats): 16*17 + 1
#define DBS    65          // dynb px-stride (floats)

typedef __attribute__((ext_vector_type(8))) short short8v;
typedef __attribute__((ext_vector_type(4))) float float4v;

__device__ inline float bf2f(unsigned short u){ return __uint_as_float(((unsigned)u)<<16); }
__device__ inline unsigned short f2bf(float f){
    unsigned u = __float_as_uint(f);
    return (unsigned short)((u + 0x7FFFu + ((u>>16)&1u)) >> 16);   // RNE
}
__device__ inline float bflo(unsigned u){ return __uint_as_float(u<<16); }
__device__ inline float bfhi(unsigned u){ return __uint_as_float(u & 0xFFFF0000u); }

__global__ __launch_bounds__(256) void cvt_wp(const float* __restrict__ Wp,
                                              unsigned short* __restrict__ Wb) {
    const int n = PREDCH * 16;
    for (int i = blockIdx.x * 256 + threadIdx.x; i < n; i += gridDim.x * 256)
        Wb[i] = f2bf(Wp[i]);
}

// One block = 18 pixels (3x6 spatial tile). Grid 256 = 1 block/CU. 576 threads (9 waves).
// Pred + Gram via mfma_f32_16x16x32_bf16 (verified layouts: A[m=lane&15][k=quad*8+j],
// B[k=quad*8+j][n=lane&15], D[row=quad*4+reg][col=lane&15]).
// K=16 zero-padded to 32; bias in k=16 slot against B=1.0.
// t-sliced: per t {pred-slice -> Gram -> QGQ accumulate}.
__global__ __launch_bounds__(576, 2) void dppc5(
    const float* __restrict__ x,
    const unsigned short* __restrict__ Wb,
    const float* __restrict__ bp,
    float* __restrict__ out)
{
    __shared__ float          xt[64 * 5 * 8];        // 10240 B  x-tile [c][r5][c8]
    __shared__ unsigned short Pt[NPX * PXS];         // 41760 B  P_t slice, bf16 [px][d][c]
    __shared__ unsigned short Qb[NPX * QBS];         // 37008 B  Q bf16 [px][o*16+j]
    __shared__ float          G [NPX * GS];          // 19656 B  Gram f32 [px][i*17+j]
    __shared__ float          Sv[BOT * NPX];         // 1152 B   s_t [d][px]
    __shared__ float          dynb[NPX * DBS];       // 4680 B   [px][o]

    const int tid  = threadIdx.x;
    const int wave = tid >> 6;
    const int lane = tid & 63;
    const int quad = lane >> 4;
    const int lrow = lane & 15;

    const int bi = blockIdx.x;
    const int b  = bi >> 7;            // 128 tiles per image
    const int r  = bi & 127;
    const int h0 = (r >> 3) * 3;
    const int w0 = (r & 7) * 6;

    // ---- Phase 1: x-tile (rows h0-1..h0+3, cols w0-1..w0+6, zero-padded) ----
    const float* xb = x + (size_t)b * CIN * LPIX;
    for (int i = tid; i < 64 * 5 * 8; i += 576) {
        const int c  = i / 40;
        const int rm = i - c * 40;
        const int r5 = rm >> 3;
        const int c8 = rm & 7;
        const int hi = h0 - 1 + r5;
        const int wi = w0 - 1 + c8;
        float v = 0.0f;
        if (hi >= 0 && hi < HH && wi >= 0 && wi < WW)
            v = xb[c * LPIX + hi * WW + wi];
        xt[i] = v;
    }
    __syncthreads();

    // ---- Build B-fragments (per lane, registers): Bf[g][nt] ----
    // element j of frag <-> k = quad*8 + j; n = lrow (pixel within N-tile)
    short8v Bf[4][2];
    #pragma unroll
    for (int g = 0; g < 4; ++g) {
        #pragma unroll
        for (int nt = 0; nt < 2; ++nt) {
            const int px = nt * 16 + lrow;
            const bool valid = (px < NPX);
            short8v f = (short8v)0;
            if (quad < 2 && valid) {
                const int pr = px / 6, pc = px - 6 * (px / 6);
                #pragma unroll
                for (int j = 0; j < 8; ++j) {
                    const int c = g * 16 + quad * 8 + j;
                    f[j] = (short)f2bf(xt[(c * 5 + pr + 1) * 8 + pc + 1]);
                }
            }
            if (quad == 2 && valid) f[0] = (short)0x3F80;   // bf16(1.0) for bias slot k=16
            Bf[g][nt] = f;
        }
    }

    // ---- Q / dyn_b part (t-independent): tiles u=0..67, all group 3 ----
    for (int u = wave; u < 68; u += 9) {
        const int ch0  = WSZ + u * 16;
        const int mych = ch0 + lrow;
        short8v a = (short8v)0;
        if (quad < 2)       a = *(const short8v*)(Wb + (size_t)mych * 16 + quad * 8);
        else if (quad == 2) a[0] = (short)f2bf(bp[mych]);
        #pragma unroll
        for (int nt = 0; nt < 2; ++nt) {
            float4v Dv = {0.f, 0.f, 0.f, 0.f};
            Dv = __builtin_amdgcn_mfma_f32_16x16x32_bf16(a, Bf[3][nt], Dv, 0, 0, 0);
            const int px = nt * 16 + lrow;
            if (px < NPX) {
                if (u < 64) {
                    uint2 pk;
                    pk.x = (unsigned)f2bf(Dv[0]) | ((unsigned)f2bf(Dv[1]) << 16);
                    pk.y = (unsigned)f2bf(Dv[2]) | ((unsigned)f2bf(Dv[3]) << 16);
                    *(uint2*)&Qb[px * QBS + u * 16 + quad * 4] = pk;
                } else {
                    const int ob = (u - 64) * 16 + quad * 4;
                    #pragma unroll
                    for (int rr = 0; rr < 4; ++rr) dynb[px * DBS + ob + rr] = Dv[rr];
                }
            }
        }
    }
    __syncthreads();

    // ---- Phase-4 state: one thread per (o-pair, px); 576 = 32*18 exactly ----
    const int o2 = tid / NPX;
    const int px4 = tid - o2 * NPX;
    const int oA = 2 * o2, oB = 2 * o2 + 1;
    float qa[16], qb[16];
    #pragma unroll
    for (int j4 = 0; j4 < 4; ++j4) {
        const uint2 ua = *(const uint2*)&Qb[px4 * QBS + oA * 16 + j4 * 4];
        qa[4*j4+0] = bflo(ua.x); qa[4*j4+1] = bfhi(ua.x);
        qa[4*j4+2] = bflo(ua.y); qa[4*j4+3] = bfhi(ua.y);
        const uint2 ub = *(const uint2*)&Qb[px4 * QBS + oB * 16 + j4 * 4];
        qb[4*j4+0] = bflo(ub.x); qb[4*j4+1] = bfhi(ub.x);
        qb[4*j4+2] = bflo(ub.y); qb[4*j4+3] = bfhi(ub.y);
    }
    float accA = dynb[px4 * DBS + oA];
    float accB = dynb[px4 * DBS + oB];

    // ==================== t-loop ====================
    for (int t = 0; t < KK; ++t) {
        const int tr = t / 3, tc = t - 3 * (t / 3);

        // ---- pred slice t: tiles (d, ct); S_t folded into epilogue ----
        for (int d = wave; d < 16; d += 9) {
            float sacc0 = 0.f, sacc1 = 0.f;
            for (int ct = 0; ct < 4; ++ct) {
                const int c0   = ct * 16;
                const int ch0  = d * 576 + c0 * 9 + t;
                const int mych = ch0 + 9 * lrow;
                short8v a = (short8v)0;
                if (quad < 2)       a = *(const short8v*)(Wb + (size_t)mych * 16 + quad * 8);
                else if (quad == 2) a[0] = (short)f2bf(bp[mych]);
                const int g0  = ch0 / GRPSZ;
                const int g1  = (ch0 + 135) / GRPSZ;
                const int myg = mych / GRPSZ;
                #pragma unroll
                for (int nt = 0; nt < 2; ++nt) {
                    float4v Dv = {0.f, 0.f, 0.f, 0.f};
                    #define PASS(GG) { short8v am = (myg == (GG)) ? a : (short8v)0; \
                        Dv = __builtin_amdgcn_mfma_f32_16x16x32_bf16(am, Bf[GG][nt], Dv, 0, 0, 0); }
                    if (g0 == 0)      { PASS(0); if (g1 == 1) PASS(1); }
                    else if (g0 == 1) { PASS(1); if (g1 == 2) PASS(2); }
                    else if (g0 == 2) { PASS(2); if (g1 == 3) PASS(3); }
                    else              { PASS(3); }
                    #undef PASS
                    const int px = nt * 16 + lrow;
                    if (px < NPX) {
                        uint2 pk;
                        pk.x = (unsigned)f2bf(Dv[0]) | ((unsigned)f2bf(Dv[1]) << 16);
                        pk.y = (unsigned)f2bf(Dv[2]) | ((unsigned)f2bf(Dv[3]) << 16);
                        *(uint2*)&Pt[px * PXS + d * 72 + c0 + quad * 4] = pk;
                        const int pr2 = px / 6 + tr;
                        const int pc2 = (px - 6 * (px / 6)) + tc;
                        float s = 0.f;
                        #pragma unroll
                        for (int rr = 0; rr < 4; ++rr) {
                            const int c = c0 + quad * 4 + rr;
                            s += Dv[rr] * xt[(c * 5 + pr2) * 8 + pc2];
                        }
                        if (nt == 0) sacc0 += s; else sacc1 += s;
                    }
                }
            }
            sacc0 += __shfl_xor(sacc0, 16); sacc0 += __shfl_xor(sacc0, 32);
            sacc1 += __shfl_xor(sacc1, 16); sacc1 += __shfl_xor(sacc1, 32);
            if (quad == 0) {
                Sv[d * NPX + lrow] = sacc0;
                if (lrow < 2) Sv[d * NPX + 16 + lrow] = sacc1;
            }
        }
        __syncthreads();

        // ---- Gram: G(px) = P_t(px) * P_t(px)^T ; A-frag == B-frag ----
        for (int gpx = wave; gpx < NPX; gpx += 9) {
            const short8v p0 = *(const short8v*)&Pt[gpx * PXS + lrow * 72 +      quad * 8];
            const short8v p1 = *(const short8v*)&Pt[gpx * PXS + lrow * 72 + 32 + quad * 8];
            float4v acc = {0.f, 0.f, 0.f, 0.f};
            acc = __builtin_amdgcn_mfma_f32_16x16x32_bf16(p0, p0, acc, 0, 0, 0);
            acc = __builtin_amdgcn_mfma_f32_16x16x32_bf16(p1, p1, acc, 0, 0, 0);
            #pragma unroll
            for (int rr = 0; rr < 4; ++rr)
                G[gpx * GS + (quad * 4 + rr) * 17 + lrow] = acc[rr];
        }
        __syncthreads();

        // ---- QGQ + s.q accumulate (1 unit per thread) ----
        {
            const float* g = &G[px4 * GS];
            float nA = 0.f, nB = 0.f;
            #pragma unroll
            for (int i = 0; i < 16; ++i) {
                const float gd = g[i * 17 + i];
                float uA = gd * qa[i];
                float uB = gd * qb[i];
                #pragma unroll
                for (int j = i + 1; j < 16; ++j) {
                    const float gv = g[i * 17 + j];
                    const float g2 = gv + gv;
                    uA += g2 * qa[j];
                    uB += g2 * qb[j];
                }
                nA += uA * qa[i];
                nB += uB * qb[i];
            }
            float dA = 0.f, dB = 0.f;
            #pragma unroll
            for (int j = 0; j < 16; ++j) {
                const float sj = Sv[j * NPX + px4];
                dA += sj * qa[j];
                dB += sj * qb[j];
            }
            accA += dA / fmaxf(sqrtf(fmaxf(nA, 0.f)), 1e-12f);
            accB += dB / fmaxf(sqrtf(fmaxf(nB, 0.f)), 1e-12f);
        }
        __syncthreads();   // before next t overwrites Pt/G/Sv
    }

    // ---- output ----
    {
        const int pr = px4 / 6, pc = px4 - 6 * (px4 / 6);
        const int l  = (h0 + pr) * WW + (w0 + pc);
        out[((size_t)b * OUTC + oA) * LPIX + l] = accA;
        out[((size_t)b * OUTC + oB) * LPIX + l] = accB;
    }
}

extern "C" void kernel_launch(void* const* d_in, const int* in_sizes, int n_in,
                              void* d_out, int out_size, void* d_ws, size_t ws_size,
                              hipStream_t stream) {
    const float* x  = (const float*)d_in[0];
    const float* Wp = (const float*)d_in[1];
    const float* bp = (const float*)d_in[2];
    float* out = (float*)d_out;
    unsigned short* Wb = (unsigned short*)d_ws;   // PREDCH*16 bf16 = 330 KB
    (void)in_sizes; (void)n_in; (void)out_size; (void)ws_size;

    hipLaunchKernelGGL(cvt_wp, dim3(160), dim3(256), 0, stream, Wp, Wb);
    hipLaunchKernelGGL(dppc5, dim3(BATCH * 128), dim3(576), 0, stream, x, Wb, bp, out);
}